// Round 10
// baseline (96.417 us; speedup 1.0000x reference)
//
#include <hip/hip_runtime.h>
#include <math.h>

#define NN 48

typedef __attribute__((ext_vector_type(8))) short bf16x8;
typedef __attribute__((ext_vector_type(4))) float f32x4;

__device__ __forceinline__ float sigmoidf_(float x) {
    return 1.0f / (1.0f + __expf(-x));
}

__device__ __forceinline__ unsigned short f2bf(float f) {
    unsigned u = __float_as_uint(f);
    return (unsigned short)((u + 0x7fffu + ((u >> 16) & 1u)) >> 16);
}

__device__ __forceinline__ unsigned packbf2(float a, float b) {
    return (unsigned)f2bf(a) | ((unsigned)f2bf(b) << 16);
}

// ================= kernel A (k_pre): fused reduce3 + x3bf emission + x2bf + weights =========
// blocks [0,2304):   reduce3 (4 pos/block, shfl tree over k) + x3->bf16 emission (x3 read ONCE)
// blocks [2304,2340): x2->bf16. block 2340: W1_3/W2_3 -> bf16 MFMA B-fragments.
// r3[pos][2c]=max_{k not in {i,j}} (0-folded), [2c+1]=min (1-folded); i==j -> 0/1.
__global__ __launch_bounds__(256) void k_pre(const float* __restrict__ x2, const float* __restrict__ x3,
        const float* __restrict__ W1, const float* __restrict__ W2,
        float* __restrict__ r3, unsigned short* __restrict__ wf,
        unsigned short* __restrict__ x2bf, unsigned short* __restrict__ x3bf, int emit) {
    int tid = threadIdx.x, blk = blockIdx.x;
    if (blk < 2304) {
        int posl = tid >> 6, l = tid & 63;
        int pos = blk * 4 + posl;              // (b*48+i)*48+j < 9216
        int j = pos % NN, i = (pos / NN) % NN;
        int cq = l & 3, kkb = l >> 2;          // cq: channel quad, kkb: 0..15
        float4 ex = make_float4(0.f, 0.f, 0.f, 0.f);
        float4 fa = make_float4(1.f, 1.f, 1.f, 1.f);
        #pragma unroll
        for (int s = 0; s < 3; ++s) {
            int kk = kkb + s * 16;             // 0..47
            size_t idx = (((size_t)pos * NN + kk) << 4) + (cq << 2);
            float4 v = *(const float4*)(x3 + idx);
            if (emit) {
                uint2 pk;
                pk.x = packbf2(v.x, v.y);
                pk.y = packbf2(v.z, v.w);
                *(uint2*)(x3bf + idx) = pk;
            }
            bool ok = (i != j) && (kk != i) && (kk != j);
            ex.x = fmaxf(ex.x, ok ? v.x : 0.f);  fa.x = fminf(fa.x, ok ? v.x : 1.f);
            ex.y = fmaxf(ex.y, ok ? v.y : 0.f);  fa.y = fminf(fa.y, ok ? v.y : 1.f);
            ex.z = fmaxf(ex.z, ok ? v.z : 0.f);  fa.z = fminf(fa.z, ok ? v.z : 1.f);
            ex.w = fmaxf(ex.w, ok ? v.w : 0.f);  fa.w = fminf(fa.w, ok ? v.w : 1.f);
        }
        #pragma unroll
        for (int m = 4; m <= 32; m <<= 1) {
            ex.x = fmaxf(ex.x, __shfl_xor(ex.x, m));  fa.x = fminf(fa.x, __shfl_xor(fa.x, m));
            ex.y = fmaxf(ex.y, __shfl_xor(ex.y, m));  fa.y = fminf(fa.y, __shfl_xor(fa.y, m));
            ex.z = fmaxf(ex.z, __shfl_xor(ex.z, m));  fa.z = fminf(fa.z, __shfl_xor(fa.z, m));
            ex.w = fmaxf(ex.w, __shfl_xor(ex.w, m));  fa.w = fminf(fa.w, __shfl_xor(fa.w, m));
        }
        if (kkb == 0) {
            float* dst = r3 + ((size_t)pos << 5) + (cq << 3);
            *(float4*)dst       = make_float4(ex.x, fa.x, ex.y, fa.y);
            *(float4*)(dst + 4) = make_float4(ex.z, fa.z, ex.w, fa.w);
        }
    } else if (blk < 2340) {
        if (!emit) return;
        int bb = blk - 2304;                   // 0..35
        #pragma unroll
        for (int q = 0; q < 4; ++q) {
            int e = bb * 1024 + q * 256 + tid; // float4 chunk < 36864
            int off = e << 2;
            float4 v = *(const float4*)(x2 + off);
            uint2 pk;
            pk.x = packbf2(v.x, v.y);
            pk.y = packbf2(v.z, v.w);
            *(uint2*)(x2bf + off) = pk;
        }
    } else {
        for (int e = tid; e < 13312; e += 256) {
            unsigned short v;
            if (e < 12288) {
                int idx = e & 7, l = (e >> 3) & 63, r = e >> 9;   // r = nt*6+ks
                int ks = r % 6, nt = r / 6;
                v = f2bf(W1[(ks * 32 + ((l >> 4) << 3) + idx) * 64 + (nt << 4) + (l & 15)]);
            } else {
                int e2 = e - 12288;
                int idx = e2 & 7, l = (e2 >> 3) & 63, ks = e2 >> 9;
                v = f2bf(W2[(ks * 32 + ((l >> 4) << 3) + idx) * 16 + (l & 15)]);
            }
            wf[e] = v;
        }
    }
}

// ================= kernel B: g0 (block 0) + g1 w/ fused reduce2 (1..48) + g2 (49..624) ==========
__global__ __launch_bounds__(256) void k_small(const float* __restrict__ x0, const float* __restrict__ x1,
        const float* __restrict__ x2, const float* __restrict__ r3,
        const float* __restrict__ W1_0, const float* __restrict__ b1_0,
        const float* __restrict__ W2_0, const float* __restrict__ b2_0,
        const float* __restrict__ W1_1, const float* __restrict__ b1_1,
        const float* __restrict__ W2_1, const float* __restrict__ b2_1,
        const float* __restrict__ W1_2, const float* __restrict__ b1_2,
        const float* __restrict__ W2_2, const float* __restrict__ b2_2,
        float* __restrict__ out) {
    __shared__ __align__(16) float smem[8960];
    int tid = threadIdx.x;
    int blk = blockIdx.x;
    if (blk == 0) {
        float* st0 = smem;            // [4][48]
        float* sh0 = smem + 192;      // [4][64]
        int b = tid >> 6, sub = (tid >> 4) & 3, c = tid & 15;
        float ex = -INFINITY, fa = INFINITY;
        for (int ii = sub * 12; ii < sub * 12 + 12; ++ii) {
            float v = x1[(b * NN + ii) * 16 + c];
            ex = fmaxf(ex, v); fa = fminf(fa, v);
        }
        ex = fmaxf(ex, __shfl_xor(ex, 16)); fa = fminf(fa, __shfl_xor(fa, 16));
        ex = fmaxf(ex, __shfl_xor(ex, 32)); fa = fminf(fa, __shfl_xor(fa, 32));
        if (sub == 0) { st0[b * 48 + 16 + 2 * c] = ex; st0[b * 48 + 17 + 2 * c] = fa; }
        if (tid < 64) st0[(tid >> 4) * 48 + (tid & 15)] = x0[tid];
        __syncthreads();
        {
            int bb = tid >> 6, ln = tid & 63;
            float h = b1_0[ln];
            for (int cc = 0; cc < 48; ++cc) h += st0[bb * 48 + cc] * W1_0[cc * 64 + ln];
            sh0[bb * 64 + ln] = fmaxf(h, 0.f);
        }
        __syncthreads();
        if (tid < 64) {
            int bb = tid >> 4, o = tid & 15;
            float acc = b2_0[o];
            for (int tt = 0; tt < 64; ++tt) acc += sh0[bb * 64 + tt] * W2_0[tt * 16 + o];
            out[bb * 16 + o] = sigmoidf_(acc);
        }
    } else if (blk <= 48) {
        int grp = tid >> 6, ln = tid & 63;
        int row = (blk - 1) * 4 + grp;             // b*48+i, < 192
        int b = row / NN, i = row % NN;
        float* sin1 = smem + grp * 64;
        float* sh1  = smem + 256 + grp * 64;
        int c = ln & 15, q = ln >> 4;
        float ex = 0.f, fa = 1.f;
        const float* xb = x2 + (size_t)row * NN * 16 + c;
        for (int jj = q * 12; jj < q * 12 + 12; ++jj) {
            float v = xb[jj * 16];
            bool ok = (jj != i);
            ex = fmaxf(ex, ok ? v : 0.f); fa = fminf(fa, ok ? v : 1.f);
        }
        ex = fmaxf(ex, __shfl_xor(ex, 16)); fa = fminf(fa, __shfl_xor(fa, 16));
        ex = fmaxf(ex, __shfl_xor(ex, 32)); fa = fminf(fa, __shfl_xor(fa, 32));
        if (q == 0) { sin1[32 + 2 * c] = ex; sin1[33 + 2 * c] = fa; }
        if (ln < 16) sin1[ln] = x0[b * 16 + ln];
        else if (ln < 32) sin1[ln] = x1[row * 16 + (ln - 16)];
        __syncthreads();
        float h = b1_1[ln];
        #pragma unroll
        for (int c4 = 0; c4 < 64; c4 += 4) {
            float4 iv = *(const float4*)&sin1[c4];
            h += iv.x * W1_1[(c4 + 0) * 64 + ln] + iv.y * W1_1[(c4 + 1) * 64 + ln]
               + iv.z * W1_1[(c4 + 2) * 64 + ln] + iv.w * W1_1[(c4 + 3) * 64 + ln];
        }
        sh1[ln] = fmaxf(h, 0.f);
        __syncthreads();
        if (ln < 16) {
            float acc = b2_1[ln];
            #pragma unroll
            for (int tt = 0; tt < 64; ++tt) acc += sh1[tt] * W2_1[tt * 16 + ln];
            out[64 + row * 16 + ln] = sigmoidf_(acc);
        }
    } else {
        float* sW1  = smem;            // 8192
        float* sin_ = smem + 8192;     // [4][128]
        float* sh   = smem + 8704;     // [4][64]
        int wv = tid >> 6, ln = tid & 63;
        for (int p = tid; p < 8192; p += 256) sW1[p] = W1_2[p];
        float bias = b1_2[ln];
        __syncthreads();
        for (int rr = 0; rr < 4; ++rr) {
            int row = (blk - 49) * 16 + rr * 4 + wv;   // (b*48+i)*48+j
            int j = row % NN;
            int bi = row / NN;
            int i = bi % NN;
            int b = bi / NN;
            for (int cc = ln; cc < 128; cc += 64) {
                int half = cc >> 6, w = cc & 63;
                int a1 = half ? j : i;
                int a2 = half ? i : j;
                float v;
                if (w < 16)      v = x1[(b * NN + a1) * 16 + w];
                else if (w < 32) v = x2[((b * NN + a1) * NN + a2) * 16 + (w - 16)];
                else             v = r3[((size_t)(b * NN + a1) * NN + a2) * 32 + (w - 32)];
                sin_[wv * 128 + cc] = v;
            }
            __syncthreads();
            float h = bias;
            #pragma unroll
            for (int c4 = 0; c4 < 128; c4 += 4) {
                float4 iv = *(const float4*)&sin_[wv * 128 + c4];
                h += iv.x * sW1[(c4 + 0) * 64 + ln] + iv.y * sW1[(c4 + 1) * 64 + ln]
                   + iv.z * sW1[(c4 + 2) * 64 + ln] + iv.w * sW1[(c4 + 3) * 64 + ln];
            }
            sh[wv * 64 + ln] = fmaxf(h, 0.f);
            __syncthreads();
            if (ln < 16) {
                float acc = b2_2[ln];
                #pragma unroll
                for (int tt = 0; tt < 64; ++tt) acc += sh[wv * 64 + tt] * W2_2[tt * 16 + ln];
                out[3136 + row * 16 + ln] = sigmoidf_(acc);
            }
            __syncthreads();
        }
    }
}

// ================= kernel C (fast): group 3 — LDS weights + 4 pairs/block =================
// Block = (pair-quad, batch b), 192 threads = 3 waves, wave = M-tile mt. Weight table
// (26.6 KB) staged in LDS ONCE per block, amortized over 4 pairs. Per (pair,mt): 3
// involution f-pairs {(0,2),(1,4),(3,5)}: 8 ds_read weight frags + 2 A-gloads + 16 MFMAs
// (each weight frag used twice: swap trick). sH is wave-private -> no barriers in pair loop.
__global__ __launch_bounds__(192) void k_g3d(const unsigned short* __restrict__ x2bf,
        const unsigned short* __restrict__ x3bf, const unsigned short* __restrict__ wf,
        const float* __restrict__ b1, const float* __restrict__ b2,
        float* __restrict__ out3) {
    __shared__ __align__(16) unsigned short sW[13312];           // 26.6 KB: w1frag+w2frag
    __shared__ __align__(16) unsigned short sH[2][6 * 64 * 8];   // 12 KB

    int tid = threadIdx.x, mt = tid >> 6, l = tid & 63;          // wave = M-tile 0..2
    int b = blockIdx.y;

    // stage weight table (identity copy, 3328 uint2)
    for (int t = tid; t < 3328; t += 192)
        *(uint2*)&sW[t * 4] = *(const uint2*)(wf + t * 4);
    __syncthreads();

    int l15 = l & 15, g = l >> 4;
    bool isx2 = (g < 2);
    int goff = (g & 1) << 3;
    const unsigned short* bp = isx2 ? x2bf : x3bf;

    float b1v[4];
    #pragma unroll
    for (int nt = 0; nt < 4; ++nt) b1v[nt] = b1[(nt << 4) + l15];
    float b2v = b2[l15];

    bf16x8 w2f[2];
    #pragma unroll
    for (int ks = 0; ks < 2; ++ks)
        w2f[ks] = *(const bf16x8*)&sW[12288 + ((ks << 6) + l) * 8];

    const int b2b = b * 36864;
    const int b3b = b * 1769472;
    const int s2_[6] = { 0, 16, 0, 768, 16, 768 };
    const int s3_[6] = { 16, 768, 16, 36864, 768, 36864 };
    const int fpa[3] = { 0, 1, 3 };                // involution pairs (fa, fb=p1[fa])
    const int fpb[3] = { 2, 4, 5 };

    #pragma unroll 1
    for (int pr = 0; pr < 4; ++pr) {
        int pp = blockIdx.x * 4 + pr, i = 0;
        while (pp >= NN - i) { pp -= NN - i; ++i; }
        int j = i + pp;                            // i <= j

        // chunk base offsets (triple (i,j)); c0..c5 as before
        const int cb2_[6] = { b2b + (i * NN + j) * 16, b2b + i * 768, b2b + (j * NN + i) * 16,
                              b2b + i * 16,            b2b + j * 768, b2b + j * 16 };
        const int cb3_[6] = { b3b + (i * NN + j) * 768, b3b + i * 36864 + j * 16, b3b + (j * NN + i) * 768,
                              b3b + i * 768 + j * 16,   b3b + j * 36864 + i * 16, b3b + j * 768 + i * 16 };
        int off_[6];
        #pragma unroll
        for (int f = 0; f < 6; ++f) {
            int s = isx2 ? s2_[f] : s3_[f];
            int base = isx2 ? cb2_[f] : cb3_[f];
            off_[f] = base + ((mt << 4) + l15) * s + goff;
        }

        f32x4 acc[4][2];
        #pragma unroll
        for (int nt = 0; nt < 4; ++nt) {
            f32x4 t = {b1v[nt], b1v[nt], b1v[nt], b1v[nt]};
            acc[nt][0] = t; acc[nt][1] = t;
        }

        #pragma unroll
        for (int fp = 0; fp < 3; ++fp) {
            int fa = fpa[fp], fb = fpb[fp];
            bf16x8 aA = *(const bf16x8*)(bp + off_[fa]);
            bf16x8 aB = *(const bf16x8*)(bp + off_[fb]);
            #pragma unroll
            for (int nt = 0; nt < 4; ++nt) {
                bf16x8 wA = *(const bf16x8*)&sW[(((nt * 6 + fa) << 6) + l) * 8];
                bf16x8 wB = *(const bf16x8*)&sW[(((nt * 6 + fb) << 6) + l) * 8];
                // f=fa: col fa -> acc0, col p1[fa]=fb -> acc1
                acc[nt][0] = __builtin_amdgcn_mfma_f32_16x16x32_bf16(aA, wA, acc[nt][0], 0, 0, 0);
                acc[nt][1] = __builtin_amdgcn_mfma_f32_16x16x32_bf16(aA, wB, acc[nt][1], 0, 0, 0);
                // f=fb: col fb -> acc0, col p1[fb]=fa -> acc1
                acc[nt][0] = __builtin_amdgcn_mfma_f32_16x16x32_bf16(aB, wB, acc[nt][0], 0, 0, 0);
                acc[nt][1] = __builtin_amdgcn_mfma_f32_16x16x32_bf16(aB, wA, acc[nt][1], 0, 0, 0);
            }
        }

        // ---- ReLU -> bf16 -> sH (layer-2 A-fragment order); wave-private segments ----
        {
            int rbase = (l >> 4) << 2;
            #pragma unroll
            for (int tr = 0; tr < 2; ++tr) {
                #pragma unroll
                for (int nt = 0; nt < 4; ++nt) {
                    int within = ((nt & 1) << 4) + l15;
                    int ks2 = nt >> 1;
                    int lhi = (within >> 3) << 4;
                    int idx = within & 7;
                    #pragma unroll
                    for (int rg = 0; rg < 4; ++rg) {
                        float h = fmaxf(acc[nt][tr][rg], 0.0f);
                        int lp = rbase + rg + lhi;
                        sH[tr][((((mt << 1) + ks2) << 6) + lp) * 8 + idx] = f2bf(h);
                    }
                }
            }
        }

        // ---- layer 2: wave mt reads its own segments (no cross-wave dep) ----
        {
            #pragma unroll
            for (int tr = 0; tr < 2; ++tr) {
                if (tr == 0 || i != j) {
                    f32x4 acc2 = {b2v, b2v, b2v, b2v};
                    #pragma unroll
                    for (int ks = 0; ks < 2; ++ks) {
                        bf16x8 a = *(const bf16x8*)&sH[tr][((((mt << 1) + ks) << 6) + l) << 3];
                        acc2 = __builtin_amdgcn_mfma_f32_16x16x32_bf16(a, w2f[ks], acc2, 0, 0, 0);
                    }
                    int triple = tr ? ((b * NN + j) * NN + i) : ((b * NN + i) * NN + j);
                    size_t obase = ((size_t)triple * NN + (mt << 4) + ((l >> 4) << 2)) * 16 + l15;
                    #pragma unroll
                    for (int rg = 0; rg < 4; ++rg)
                        out3[obase + (size_t)rg * 16] = sigmoidf_(acc2[rg]);
                }
            }
        }
    }
}

// ================= kernel C (fallback): round-4-verified fp32 staged version =================
__global__ __launch_bounds__(256) void k_g3m(const float* __restrict__ x2, const float* __restrict__ x3,
                                             const unsigned short* __restrict__ wf,
                                             const float* __restrict__ b1, const float* __restrict__ b2,
                                             float* __restrict__ out3) {
    __shared__ __align__(16) unsigned short sA[18 * 64 * 8];
    __shared__ __align__(16) unsigned short sH[6 * 64 * 8];

    int tid = threadIdx.x;
    int wv = tid >> 6, l = tid & 63;
    int triple = blockIdx.x;
    int j = triple % NN;
    int bi = triple / NN;
    int i = bi % NN;
    int b = bi / NN;

    bf16x8 w1f[6];
    #pragma unroll
    for (int ks = 0; ks < 6; ++ks)
        w1f[ks] = *(const bf16x8*)(wf + (((wv * 6 + ks) << 6) + l) * 8);
    bf16x8 w2f[2];
    #pragma unroll
    for (int ks = 0; ks < 2; ++ks)
        w2f[ks] = *(const bf16x8*)(wf + 12288 + ((ks << 6) + l) * 8);

    const int x2b = b * NN * NN * 16;
    const int x3b = b * NN * NN * NN * 16;

    #pragma unroll
    for (int it = 0; it < 9; ++it) {
        int t = it * 256 + tid;
        int fs = __builtin_amdgcn_readfirstlane(t >> 7);
        int mt = fs / 6;
        int ks = fs - mt * 6;
        int lp = (t >> 1) & 63;
        int kk = (mt << 4) + (lp & 15);
        int w = ((lp >> 4) << 3) + ((t & 1) << 2);
        int a1, a2, a3;
        switch (ks) {
            case 0:  a1 = i;  a2 = j;  a3 = kk; break;
            case 1:  a1 = i;  a2 = kk; a3 = j;  break;
            case 2:  a1 = j;  a2 = i;  a3 = kk; break;
            case 3:  a1 = kk; a2 = i;  a3 = j;  break;
            case 4:  a1 = j;  a2 = kk; a3 = i;  break;
            default: a1 = kk; a2 = j;  a3 = i;  break;
        }
        const float* p2 = x2 + x2b + (a1 * NN + a2) * 16 + w;
        const float* p3 = x3 + x3b + ((a1 * NN + a2) * NN + a3) * 16 + (w - 16);
        const float* p = (w < 16) ? p2 : p3;
        float4 v = *(const float4*)p;
        uint2 pk;
        pk.x = packbf2(v.x, v.y);
        pk.y = packbf2(v.z, v.w);
        *(uint2*)&sA[t * 4] = pk;
    }
    __syncthreads();

    float bv = b1[(wv << 4) + (l & 15)];
    f32x4 acc0 = {bv, bv, bv, bv};
    f32x4 acc1 = acc0, acc2 = acc0;
    #pragma unroll
    for (int ks = 0; ks < 6; ++ks) {
        bf16x8 a0  = *(const bf16x8*)&sA[(((0 * 6 + ks) << 6) + l) << 3];
        bf16x8 a1_ = *(const bf16x8*)&sA[(((1 * 6 + ks) << 6) + l) << 3];
        bf16x8 a2_ = *(const bf16x8*)&sA[(((2 * 6 + ks) << 6) + l) << 3];
        acc0 = __builtin_amdgcn_mfma_f32_16x16x32_bf16(a0,  w1f[ks], acc0, 0, 0, 0);
        acc1 = __builtin_amdgcn_mfma_f32_16x16x32_bf16(a1_, w1f[ks], acc1, 0, 0, 0);
        acc2 = __builtin_amdgcn_mfma_f32_16x16x32_bf16(a2_, w1f[ks], acc2, 0, 0, 0);
    }

    {
        int within = ((wv & 1) << 4) + (l & 15);
        int ks2 = wv >> 1;
        int lhi = (within >> 3) << 4;
        int idx = within & 7;
        int rbase = (l >> 4) << 2;
        #pragma unroll
        for (int mt = 0; mt < 3; ++mt) {
            f32x4 a = (mt == 0) ? acc0 : (mt == 1) ? acc1 : acc2;
            #pragma unroll
            for (int rg = 0; rg < 4; ++rg) {
                float h = fmaxf(a[rg], 0.0f);
                int lp = rbase + rg + lhi;
                sH[((((mt << 1) + ks2) << 6) + lp) * 8 + idx] = f2bf(h);
            }
        }
    }
    __syncthreads();

    if (wv < 3) {
        int mt = wv;
        float bv2 = b2[l & 15];
        f32x4 acc = {bv2, bv2, bv2, bv2};
        #pragma unroll
        for (int ks = 0; ks < 2; ++ks) {
            bf16x8 a = *(const bf16x8*)&sH[((((mt << 1) + ks) << 6) + l) << 3];
            acc = __builtin_amdgcn_mfma_f32_16x16x32_bf16(a, w2f[ks], acc, 0, 0, 0);
        }
        size_t obase = ((size_t)triple * NN + (mt << 4) + ((l >> 4) << 2)) * 16 + (l & 15);
        #pragma unroll
        for (int rg = 0; rg < 4; ++rg)
            out3[obase + (size_t)rg * 16] = sigmoidf_(acc[rg]);
    }
}

extern "C" void kernel_launch(void* const* d_in, const int* in_sizes, int n_in,
                              void* d_out, int out_size, void* d_ws, size_t ws_size,
                              hipStream_t stream) {
    const float* x0 = (const float*)d_in[0];
    const float* x1 = (const float*)d_in[1];
    const float* x2 = (const float*)d_in[2];
    const float* x3 = (const float*)d_in[3];
    const float* W1_0 = (const float*)d_in[4];
    const float* b1_0 = (const float*)d_in[5];
    const float* W2_0 = (const float*)d_in[6];
    const float* b2_0 = (const float*)d_in[7];
    const float* W1_1 = (const float*)d_in[8];
    const float* b1_1 = (const float*)d_in[9];
    const float* W2_1 = (const float*)d_in[10];
    const float* b2_1 = (const float*)d_in[11];
    const float* W1_2 = (const float*)d_in[12];
    const float* b1_2 = (const float*)d_in[13];
    const float* W2_2 = (const float*)d_in[14];
    const float* b2_2 = (const float*)d_in[15];
    const float* W1_3 = (const float*)d_in[16];
    const float* b1_3 = (const float*)d_in[17];
    const float* W2_3 = (const float*)d_in[18];
    const float* b2_3 = (const float*)d_in[19];

    float* out = (float*)d_out;
    float* r3 = (float*)d_ws;                               // 294912 f32
    unsigned short* wf   = (unsigned short*)(r3 + 294912);  // 13312 bf16
    unsigned short* x2bf = wf + 13312;                      // 147456 bf16
    unsigned short* x3bf = x2bf + 147456;                   // 7077888 bf16
    size_t need = (size_t)294912 * 4 + (size_t)(13312 + 147456 + 7077888) * 2;  // ~15.66 MB
    int fast = (ws_size >= need) ? 1 : 0;

    hipLaunchKernelGGL(k_pre, dim3(2341), dim3(256), 0, stream,
                       x2, x3, W1_3, W2_3, r3, wf, x2bf, x3bf, fast);
    if (fast)
        hipLaunchKernelGGL(k_g3d, dim3(294, 4), dim3(192), 0, stream,
                           x2bf, x3bf, wf, b1_3, b2_3, out + 150592);
    else
        hipLaunchKernelGGL(k_g3m, dim3(9216), dim3(256), 0, stream,
                           x2, x3, wf, b1_3, b2_3, out + 150592);
    hipLaunchKernelGGL(k_small, dim3(625), dim3(256), 0, stream,
                       x0, x1, x2, r3,
                       W1_0, b1_0, W2_0, b2_0,
                       W1_1, b1_1, W2_1, b2_1,
                       W1_2, b1_2, W2_2, b2_2,
                       out);
}

// Round 11
// 85.359 us; speedup vs baseline: 1.1295x; 1.1295x over previous
//
#include <hip/hip_runtime.h>
#include <math.h>

#define NN 48

typedef __attribute__((ext_vector_type(8))) short bf16x8;
typedef __attribute__((ext_vector_type(4))) float f32x4;

__device__ __forceinline__ float sigmoidf_(float x) {
    return 1.0f / (1.0f + __expf(-x));
}

__device__ __forceinline__ unsigned short f2bf(float f) {
    unsigned u = __float_as_uint(f);
    return (unsigned short)((u + 0x7fffu + ((u >> 16) & 1u)) >> 16);
}

__device__ __forceinline__ unsigned packbf2(float a, float b) {
    return (unsigned)f2bf(a) | ((unsigned)f2bf(b) << 16);
}

// ================= kernel A (k_pre): fused reduce3 + x3bf emission + x2bf + weights =========
// blocks [0,2304):   reduce3 (4 pos/block, shfl tree over k) + x3->bf16 emission (x3 read ONCE)
// blocks [2304,2340): x2->bf16. block 2340: W1_3/W2_3 -> bf16 MFMA B-fragments.
// r3[pos][2c]=max_{k not in {i,j}} (0-folded), [2c+1]=min (1-folded); i==j -> 0/1.
__global__ __launch_bounds__(256) void k_pre(const float* __restrict__ x2, const float* __restrict__ x3,
        const float* __restrict__ W1, const float* __restrict__ W2,
        float* __restrict__ r3, unsigned short* __restrict__ wf,
        unsigned short* __restrict__ x2bf, unsigned short* __restrict__ x3bf, int emit) {
    int tid = threadIdx.x, blk = blockIdx.x;
    if (blk < 2304) {
        int posl = tid >> 6, l = tid & 63;
        int pos = blk * 4 + posl;              // (b*48+i)*48+j < 9216
        int j = pos % NN, i = (pos / NN) % NN;
        int cq = l & 3, kkb = l >> 2;          // cq: channel quad, kkb: 0..15
        float4 ex = make_float4(0.f, 0.f, 0.f, 0.f);
        float4 fa = make_float4(1.f, 1.f, 1.f, 1.f);
        #pragma unroll
        for (int s = 0; s < 3; ++s) {
            int kk = kkb + s * 16;             // 0..47
            size_t idx = (((size_t)pos * NN + kk) << 4) + (cq << 2);
            float4 v = *(const float4*)(x3 + idx);
            if (emit) {
                uint2 pk;
                pk.x = packbf2(v.x, v.y);
                pk.y = packbf2(v.z, v.w);
                *(uint2*)(x3bf + idx) = pk;
            }
            bool ok = (i != j) && (kk != i) && (kk != j);
            ex.x = fmaxf(ex.x, ok ? v.x : 0.f);  fa.x = fminf(fa.x, ok ? v.x : 1.f);
            ex.y = fmaxf(ex.y, ok ? v.y : 0.f);  fa.y = fminf(fa.y, ok ? v.y : 1.f);
            ex.z = fmaxf(ex.z, ok ? v.z : 0.f);  fa.z = fminf(fa.z, ok ? v.z : 1.f);
            ex.w = fmaxf(ex.w, ok ? v.w : 0.f);  fa.w = fminf(fa.w, ok ? v.w : 1.f);
        }
        #pragma unroll
        for (int m = 4; m <= 32; m <<= 1) {
            ex.x = fmaxf(ex.x, __shfl_xor(ex.x, m));  fa.x = fminf(fa.x, __shfl_xor(fa.x, m));
            ex.y = fmaxf(ex.y, __shfl_xor(ex.y, m));  fa.y = fminf(fa.y, __shfl_xor(fa.y, m));
            ex.z = fmaxf(ex.z, __shfl_xor(ex.z, m));  fa.z = fminf(fa.z, __shfl_xor(fa.z, m));
            ex.w = fmaxf(ex.w, __shfl_xor(ex.w, m));  fa.w = fminf(fa.w, __shfl_xor(fa.w, m));
        }
        if (kkb == 0) {
            float* dst = r3 + ((size_t)pos << 5) + (cq << 3);
            *(float4*)dst       = make_float4(ex.x, fa.x, ex.y, fa.y);
            *(float4*)(dst + 4) = make_float4(ex.z, fa.z, ex.w, fa.w);
        }
    } else if (blk < 2340) {
        if (!emit) return;
        int bb = blk - 2304;                   // 0..35
        #pragma unroll
        for (int q = 0; q < 4; ++q) {
            int e = bb * 1024 + q * 256 + tid; // float4 chunk < 36864
            int off = e << 2;
            float4 v = *(const float4*)(x2 + off);
            uint2 pk;
            pk.x = packbf2(v.x, v.y);
            pk.y = packbf2(v.z, v.w);
            *(uint2*)(x2bf + off) = pk;
        }
    } else {
        for (int e = tid; e < 13312; e += 256) {
            unsigned short v;
            if (e < 12288) {
                int idx = e & 7, l = (e >> 3) & 63, r = e >> 9;   // r = nt*6+ks
                int ks = r % 6, nt = r / 6;
                v = f2bf(W1[(ks * 32 + ((l >> 4) << 3) + idx) * 64 + (nt << 4) + (l & 15)]);
            } else {
                int e2 = e - 12288;
                int idx = e2 & 7, l = (e2 >> 3) & 63, ks = e2 >> 9;
                v = f2bf(W2[(ks * 32 + ((l >> 4) << 3) + idx) * 16 + (l & 15)]);
            }
            wf[e] = v;
        }
    }
}

// ================= kernel B: g0 (block 0) + g1 w/ fused reduce2 (1..48) + g2 (49..624) ==========
__global__ __launch_bounds__(256) void k_small(const float* __restrict__ x0, const float* __restrict__ x1,
        const float* __restrict__ x2, const float* __restrict__ r3,
        const float* __restrict__ W1_0, const float* __restrict__ b1_0,
        const float* __restrict__ W2_0, const float* __restrict__ b2_0,
        const float* __restrict__ W1_1, const float* __restrict__ b1_1,
        const float* __restrict__ W2_1, const float* __restrict__ b2_1,
        const float* __restrict__ W1_2, const float* __restrict__ b1_2,
        const float* __restrict__ W2_2, const float* __restrict__ b2_2,
        float* __restrict__ out) {
    __shared__ __align__(16) float smem[8960];
    int tid = threadIdx.x;
    int blk = blockIdx.x;
    if (blk == 0) {
        float* st0 = smem;            // [4][48]
        float* sh0 = smem + 192;      // [4][64]
        int b = tid >> 6, sub = (tid >> 4) & 3, c = tid & 15;
        float ex = -INFINITY, fa = INFINITY;
        for (int ii = sub * 12; ii < sub * 12 + 12; ++ii) {
            float v = x1[(b * NN + ii) * 16 + c];
            ex = fmaxf(ex, v); fa = fminf(fa, v);
        }
        ex = fmaxf(ex, __shfl_xor(ex, 16)); fa = fminf(fa, __shfl_xor(fa, 16));
        ex = fmaxf(ex, __shfl_xor(ex, 32)); fa = fminf(fa, __shfl_xor(fa, 32));
        if (sub == 0) { st0[b * 48 + 16 + 2 * c] = ex; st0[b * 48 + 17 + 2 * c] = fa; }
        if (tid < 64) st0[(tid >> 4) * 48 + (tid & 15)] = x0[tid];
        __syncthreads();
        {
            int bb = tid >> 6, ln = tid & 63;
            float h = b1_0[ln];
            for (int cc = 0; cc < 48; ++cc) h += st0[bb * 48 + cc] * W1_0[cc * 64 + ln];
            sh0[bb * 64 + ln] = fmaxf(h, 0.f);
        }
        __syncthreads();
        if (tid < 64) {
            int bb = tid >> 4, o = tid & 15;
            float acc = b2_0[o];
            for (int tt = 0; tt < 64; ++tt) acc += sh0[bb * 64 + tt] * W2_0[tt * 16 + o];
            out[bb * 16 + o] = sigmoidf_(acc);
        }
    } else if (blk <= 48) {
        int grp = tid >> 6, ln = tid & 63;
        int row = (blk - 1) * 4 + grp;             // b*48+i, < 192
        int b = row / NN, i = row % NN;
        float* sin1 = smem + grp * 64;
        float* sh1  = smem + 256 + grp * 64;
        int c = ln & 15, q = ln >> 4;
        float ex = 0.f, fa = 1.f;
        const float* xb = x2 + (size_t)row * NN * 16 + c;
        for (int jj = q * 12; jj < q * 12 + 12; ++jj) {
            float v = xb[jj * 16];
            bool ok = (jj != i);
            ex = fmaxf(ex, ok ? v : 0.f); fa = fminf(fa, ok ? v : 1.f);
        }
        ex = fmaxf(ex, __shfl_xor(ex, 16)); fa = fminf(fa, __shfl_xor(fa, 16));
        ex = fmaxf(ex, __shfl_xor(ex, 32)); fa = fminf(fa, __shfl_xor(fa, 32));
        if (q == 0) { sin1[32 + 2 * c] = ex; sin1[33 + 2 * c] = fa; }
        if (ln < 16) sin1[ln] = x0[b * 16 + ln];
        else if (ln < 32) sin1[ln] = x1[row * 16 + (ln - 16)];
        __syncthreads();
        float h = b1_1[ln];
        #pragma unroll
        for (int c4 = 0; c4 < 64; c4 += 4) {
            float4 iv = *(const float4*)&sin1[c4];
            h += iv.x * W1_1[(c4 + 0) * 64 + ln] + iv.y * W1_1[(c4 + 1) * 64 + ln]
               + iv.z * W1_1[(c4 + 2) * 64 + ln] + iv.w * W1_1[(c4 + 3) * 64 + ln];
        }
        sh1[ln] = fmaxf(h, 0.f);
        __syncthreads();
        if (ln < 16) {
            float acc = b2_1[ln];
            #pragma unroll
            for (int tt = 0; tt < 64; ++tt) acc += sh1[tt] * W2_1[tt * 16 + ln];
            out[64 + row * 16 + ln] = sigmoidf_(acc);
        }
    } else {
        float* sW1  = smem;            // 8192
        float* sin_ = smem + 8192;     // [4][128]
        float* sh   = smem + 8704;     // [4][64]
        int wv = tid >> 6, ln = tid & 63;
        for (int p = tid; p < 8192; p += 256) sW1[p] = W1_2[p];
        float bias = b1_2[ln];
        __syncthreads();
        for (int rr = 0; rr < 4; ++rr) {
            int row = (blk - 49) * 16 + rr * 4 + wv;   // (b*48+i)*48+j
            int j = row % NN;
            int bi = row / NN;
            int i = bi % NN;
            int b = bi / NN;
            for (int cc = ln; cc < 128; cc += 64) {
                int half = cc >> 6, w = cc & 63;
                int a1 = half ? j : i;
                int a2 = half ? i : j;
                float v;
                if (w < 16)      v = x1[(b * NN + a1) * 16 + w];
                else if (w < 32) v = x2[((b * NN + a1) * NN + a2) * 16 + (w - 16)];
                else             v = r3[((size_t)(b * NN + a1) * NN + a2) * 32 + (w - 32)];
                sin_[wv * 128 + cc] = v;
            }
            __syncthreads();
            float h = bias;
            #pragma unroll
            for (int c4 = 0; c4 < 128; c4 += 4) {
                float4 iv = *(const float4*)&sin_[wv * 128 + c4];
                h += iv.x * sW1[(c4 + 0) * 64 + ln] + iv.y * sW1[(c4 + 1) * 64 + ln]
                   + iv.z * sW1[(c4 + 2) * 64 + ln] + iv.w * sW1[(c4 + 3) * 64 + ln];
            }
            sh[wv * 64 + ln] = fmaxf(h, 0.f);
            __syncthreads();
            if (ln < 16) {
                float acc = b2_2[ln];
                #pragma unroll
                for (int tt = 0; tt < 64; ++tt) acc += sh[wv * 64 + tt] * W2_2[tt * 16 + ln];
                out[3136 + row * 16 + ln] = sigmoidf_(acc);
            }
            __syncthreads();
        }
    }
}

// ================= kernel C (fast): group 3 — staged pair-shared MFMA (k_g3p) =================
// Block = (pair i<=j, batch b), 256 threads = 4 waves, wave = N-tile wv. Stage the 18 KB
// chunk tile of triple (i,j) ONCE (r4-verified task map, bf16 uint2 loads); triple (j,i)'s
// chunk f equals triple (i,j)'s chunk p1[f] (involution {2,4,0,5,1,3}), so each ds_read
// fragment feeds 2 MFMAs. 30 KB LDS -> 5 blocks/CU. 40 MFMAs/wave vs r4's 20.
__global__ __launch_bounds__(256) void k_g3p(const unsigned short* __restrict__ x2bf,
        const unsigned short* __restrict__ x3bf, const unsigned short* __restrict__ wf,
        const float* __restrict__ b1, const float* __restrict__ b2,
        float* __restrict__ out3) {
    __shared__ __align__(16) unsigned short sA[18 * 64 * 8];     // 18 KB, [mt*6+ks][lane][8]
    __shared__ __align__(16) unsigned short sH[2][6 * 64 * 8];   // 12 KB

    int tid = threadIdx.x;
    int wv = tid >> 6, l = tid & 63;              // wave = N-tile
    int pp = blockIdx.x, i = 0;
    while (pp >= NN - i) { pp -= NN - i; ++i; }
    int j = i + pp;                               // i <= j
    int b = blockIdx.y;

    bf16x8 w1f[6];
    #pragma unroll
    for (int ks = 0; ks < 6; ++ks)
        w1f[ks] = *(const bf16x8*)(wf + (((wv * 6 + ks) << 6) + l) * 8);
    bf16x8 w2f[2];
    #pragma unroll
    for (int ks = 0; ks < 2; ++ks)
        w2f[ks] = *(const bf16x8*)(wf + 12288 + ((ks << 6) + l) * 8);

    const int x2b = b * 36864;
    const int x3b = b * 1769472;

    // ---- stage triple (i,j)'s 48x192 tile (bf16), r4-verified task->LDS map ----
    #pragma unroll
    for (int it = 0; it < 9; ++it) {
        int t = it * 256 + tid;
        int fs = __builtin_amdgcn_readfirstlane(t >> 7);
        int mt = fs / 6;
        int ks = fs - mt * 6;
        int lp = (t >> 1) & 63;
        int kk = (mt << 4) + (lp & 15);
        int w = ((lp >> 4) << 3) + ((t & 1) << 2);
        int a1, a2, a3;
        switch (ks) {
            case 0:  a1 = i;  a2 = j;  a3 = kk; break;
            case 1:  a1 = i;  a2 = kk; a3 = j;  break;
            case 2:  a1 = j;  a2 = i;  a3 = kk; break;
            case 3:  a1 = kk; a2 = i;  a3 = j;  break;
            case 4:  a1 = j;  a2 = kk; a3 = i;  break;
            default: a1 = kk; a2 = j;  a3 = i;  break;
        }
        const unsigned short* p2 = x2bf + x2b + (a1 * NN + a2) * 16 + w;
        const unsigned short* p3 = x3bf + x3b + ((a1 * NN + a2) * NN + a3) * 16 + (w - 16);
        const unsigned short* p = (w < 16) ? p2 : p3;
        *(uint2*)&sA[t * 4] = *(const uint2*)p;
    }
    __syncthreads();

    // ---- layer 1: per (mt,ks) one ds_read feeds both triples ----
    float bv = b1[(wv << 4) + (l & 15)];
    f32x4 acc0[3], acc1[3];
    #pragma unroll
    for (int mt = 0; mt < 3; ++mt) {
        f32x4 t = {bv, bv, bv, bv};
        acc0[mt] = t; acc1[mt] = t;
    }
    const int p1q[6] = { 2, 4, 0, 5, 1, 3 };
    #pragma unroll
    for (int ks = 0; ks < 6; ++ks) {
        bf16x8 a0 = *(const bf16x8*)&sA[(((0 * 6 + ks) << 6) + l) << 3];
        bf16x8 a1_ = *(const bf16x8*)&sA[(((1 * 6 + ks) << 6) + l) << 3];
        bf16x8 a2_ = *(const bf16x8*)&sA[(((2 * 6 + ks) << 6) + l) << 3];
        acc0[0] = __builtin_amdgcn_mfma_f32_16x16x32_bf16(a0,  w1f[ks],      acc0[0], 0, 0, 0);
        acc1[0] = __builtin_amdgcn_mfma_f32_16x16x32_bf16(a0,  w1f[p1q[ks]], acc1[0], 0, 0, 0);
        acc0[1] = __builtin_amdgcn_mfma_f32_16x16x32_bf16(a1_, w1f[ks],      acc0[1], 0, 0, 0);
        acc1[1] = __builtin_amdgcn_mfma_f32_16x16x32_bf16(a1_, w1f[p1q[ks]], acc1[1], 0, 0, 0);
        acc0[2] = __builtin_amdgcn_mfma_f32_16x16x32_bf16(a2_, w1f[ks],      acc0[2], 0, 0, 0);
        acc1[2] = __builtin_amdgcn_mfma_f32_16x16x32_bf16(a2_, w1f[p1q[ks]], acc1[2], 0, 0, 0);
    }

    // ---- ReLU -> bf16 -> sH (layer-2 A-fragment order), both triples (r4/r8 epilogue) ----
    {
        int within = ((wv & 1) << 4) + (l & 15);   // hc & 31
        int ks2 = wv >> 1;                         // hc >> 5
        int lhi = (within >> 3) << 4;
        int idx = within & 7;
        int rbase = (l >> 4) << 2;
        #pragma unroll
        for (int tr = 0; tr < 2; ++tr) {
            #pragma unroll
            for (int mt = 0; mt < 3; ++mt) {
                f32x4 a = tr ? acc1[mt] : acc0[mt];
                #pragma unroll
                for (int rg = 0; rg < 4; ++rg) {
                    float h = fmaxf(a[rg], 0.0f);
                    int lp = rbase + rg + lhi;
                    sH[tr][((((mt << 1) + ks2) << 6) + lp) * 8 + idx] = f2bf(h);
                }
            }
        }
    }
    __syncthreads();

    // ---- layer 2: waves 0-2, M-tile = wv, both triples ----
    if (wv < 3) {
        int mt = wv;
        float bv2 = b2[l & 15];
        #pragma unroll
        for (int tr = 0; tr < 2; ++tr) {
            if (tr == 0 || i != j) {
                f32x4 acc2 = {bv2, bv2, bv2, bv2};
                #pragma unroll
                for (int ks = 0; ks < 2; ++ks) {
                    bf16x8 a = *(const bf16x8*)&sH[tr][((((mt << 1) + ks) << 6) + l) << 3];
                    acc2 = __builtin_amdgcn_mfma_f32_16x16x32_bf16(a, w2f[ks], acc2, 0, 0, 0);
                }
                int triple = tr ? ((b * NN + j) * NN + i) : ((b * NN + i) * NN + j);
                size_t obase = ((size_t)triple * NN + (mt << 4) + ((l >> 4) << 2)) * 16 + (l & 15);
                #pragma unroll
                for (int rg = 0; rg < 4; ++rg)
                    out3[obase + (size_t)rg * 16] = sigmoidf_(acc2[rg]);
            }
        }
    }
}

// ================= kernel C (fallback): round-4-verified fp32 staged version =================
__global__ __launch_bounds__(256) void k_g3m(const float* __restrict__ x2, const float* __restrict__ x3,
                                             const unsigned short* __restrict__ wf,
                                             const float* __restrict__ b1, const float* __restrict__ b2,
                                             float* __restrict__ out3) {
    __shared__ __align__(16) unsigned short sA[18 * 64 * 8];
    __shared__ __align__(16) unsigned short sH[6 * 64 * 8];

    int tid = threadIdx.x;
    int wv = tid >> 6, l = tid & 63;
    int triple = blockIdx.x;
    int j = triple % NN;
    int bi = triple / NN;
    int i = bi % NN;
    int b = bi / NN;

    bf16x8 w1f[6];
    #pragma unroll
    for (int ks = 0; ks < 6; ++ks)
        w1f[ks] = *(const bf16x8*)(wf + (((wv * 6 + ks) << 6) + l) * 8);
    bf16x8 w2f[2];
    #pragma unroll
    for (int ks = 0; ks < 2; ++ks)
        w2f[ks] = *(const bf16x8*)(wf + 12288 + ((ks << 6) + l) * 8);

    const int x2b = b * NN * NN * 16;
    const int x3b = b * NN * NN * NN * 16;

    #pragma unroll
    for (int it = 0; it < 9; ++it) {
        int t = it * 256 + tid;
        int fs = __builtin_amdgcn_readfirstlane(t >> 7);
        int mt = fs / 6;
        int ks = fs - mt * 6;
        int lp = (t >> 1) & 63;
        int kk = (mt << 4) + (lp & 15);
        int w = ((lp >> 4) << 3) + ((t & 1) << 2);
        int a1, a2, a3;
        switch (ks) {
            case 0:  a1 = i;  a2 = j;  a3 = kk; break;
            case 1:  a1 = i;  a2 = kk; a3 = j;  break;
            case 2:  a1 = j;  a2 = i;  a3 = kk; break;
            case 3:  a1 = kk; a2 = i;  a3 = j;  break;
            case 4:  a1 = j;  a2 = kk; a3 = i;  break;
            default: a1 = kk; a2 = j;  a3 = i;  break;
        }
        const float* p2 = x2 + x2b + (a1 * NN + a2) * 16 + w;
        const float* p3 = x3 + x3b + ((a1 * NN + a2) * NN + a3) * 16 + (w - 16);
        const float* p = (w < 16) ? p2 : p3;
        float4 v = *(const float4*)p;
        uint2 pk;
        pk.x = packbf2(v.x, v.y);
        pk.y = packbf2(v.z, v.w);
        *(uint2*)&sA[t * 4] = pk;
    }
    __syncthreads();

    float bv = b1[(wv << 4) + (l & 15)];
    f32x4 acc0 = {bv, bv, bv, bv};
    f32x4 acc1 = acc0, acc2 = acc0;
    #pragma unroll
    for (int ks = 0; ks < 6; ++ks) {
        bf16x8 a0  = *(const bf16x8*)&sA[(((0 * 6 + ks) << 6) + l) << 3];
        bf16x8 a1_ = *(const bf16x8*)&sA[(((1 * 6 + ks) << 6) + l) << 3];
        bf16x8 a2_ = *(const bf16x8*)&sA[(((2 * 6 + ks) << 6) + l) << 3];
        acc0 = __builtin_amdgcn_mfma_f32_16x16x32_bf16(a0,  w1f[ks], acc0, 0, 0, 0);
        acc1 = __builtin_amdgcn_mfma_f32_16x16x32_bf16(a1_, w1f[ks], acc1, 0, 0, 0);
        acc2 = __builtin_amdgcn_mfma_f32_16x16x32_bf16(a2_, w1f[ks], acc2, 0, 0, 0);
    }

    {
        int within = ((wv & 1) << 4) + (l & 15);
        int ks2 = wv >> 1;
        int lhi = (within >> 3) << 4;
        int idx = within & 7;
        int rbase = (l >> 4) << 2;
        #pragma unroll
        for (int mt = 0; mt < 3; ++mt) {
            f32x4 a = (mt == 0) ? acc0 : (mt == 1) ? acc1 : acc2;
            #pragma unroll
            for (int rg = 0; rg < 4; ++rg) {
                float h = fmaxf(a[rg], 0.0f);
                int lp = rbase + rg + lhi;
                sH[((((mt << 1) + ks2) << 6) + lp) * 8 + idx] = f2bf(h);
            }
        }
    }
    __syncthreads();

    if (wv < 3) {
        int mt = wv;
        float bv2 = b2[l & 15];
        f32x4 acc = {bv2, bv2, bv2, bv2};
        #pragma unroll
        for (int ks = 0; ks < 2; ++ks) {
            bf16x8 a = *(const bf16x8*)&sH[((((mt << 1) + ks) << 6) + l) << 3];
            acc = __builtin_amdgcn_mfma_f32_16x16x32_bf16(a, w2f[ks], acc, 0, 0, 0);
        }
        size_t obase = ((size_t)triple * NN + (mt << 4) + ((l >> 4) << 2)) * 16 + (l & 15);
        #pragma unroll
        for (int rg = 0; rg < 4; ++rg)
            out3[obase + (size_t)rg * 16] = sigmoidf_(acc[rg]);
    }
}

extern "C" void kernel_launch(void* const* d_in, const int* in_sizes, int n_in,
                              void* d_out, int out_size, void* d_ws, size_t ws_size,
                              hipStream_t stream) {
    const float* x0 = (const float*)d_in[0];
    const float* x1 = (const float*)d_in[1];
    const float* x2 = (const float*)d_in[2];
    const float* x3 = (const float*)d_in[3];
    const float* W1_0 = (const float*)d_in[4];
    const float* b1_0 = (const float*)d_in[5];
    const float* W2_0 = (const float*)d_in[6];
    const float* b2_0 = (const float*)d_in[7];
    const float* W1_1 = (const float*)d_in[8];
    const float* b1_1 = (const float*)d_in[9];
    const float* W2_1 = (const float*)d_in[10];
    const float* b2_1 = (const float*)d_in[11];
    const float* W1_2 = (const float*)d_in[12];
    const float* b1_2 = (const float*)d_in[13];
    const float* W2_2 = (const float*)d_in[14];
    const float* b2_2 = (const float*)d_in[15];
    const float* W1_3 = (const float*)d_in[16];
    const float* b1_3 = (const float*)d_in[17];
    const float* W2_3 = (const float*)d_in[18];
    const float* b2_3 = (const float*)d_in[19];

    float* out = (float*)d_out;
    float* r3 = (float*)d_ws;                               // 294912 f32
    unsigned short* wf   = (unsigned short*)(r3 + 294912);  // 13312 bf16
    unsigned short* x2bf = wf + 13312;                      // 147456 bf16
    unsigned short* x3bf = x2bf + 147456;                   // 7077888 bf16
    size_t need = (size_t)294912 * 4 + (size_t)(13312 + 147456 + 7077888) * 2;  // ~15.66 MB
    int fast = (ws_size >= need) ? 1 : 0;

    hipLaunchKernelGGL(k_pre, dim3(2341), dim3(256), 0, stream,
                       x2, x3, W1_3, W2_3, r3, wf, x2bf, x3bf, fast);
    if (fast)
        hipLaunchKernelGGL(k_g3p, dim3(1176, 4), dim3(256), 0, stream,
                           x2bf, x3bf, wf, b1_3, b2_3, out + 150592);
    else
        hipLaunchKernelGGL(k_g3m, dim3(9216), dim3(256), 0, stream,
                           x2, x3, wf, b1_3, b2_3, out + 150592);
    hipLaunchKernelGGL(k_small, dim3(625), dim3(256), 0, stream,
                       x0, x1, x2, r3,
                       W1_0, b1_0, W2_0, b2_0,
                       W1_1, b1_1, W2_1, b2_1,
                       W1_2, b1_2, W2_2, b2_2,
                       out);
}

// Round 12
// 80.339 us; speedup vs baseline: 1.2001x; 1.0625x over previous
//
#include <hip/hip_runtime.h>
#include <hip/hip_bf16.h>
#include <math.h>

#define NN 48

typedef __attribute__((ext_vector_type(8))) short bf16x8;
typedef __attribute__((ext_vector_type(4))) float f32x4;

__device__ __forceinline__ float sigmoidf_(float x) {
    return 1.0f / (1.0f + __expf(-x));
}

// RNE fp32->bf16 via HIP intrinsic (compiler pairs into v_cvt_pk_bf16_f32; m240)
__device__ __forceinline__ unsigned short f2bf(float f) {
    __hip_bfloat16 h = __float2bfloat16(f);
    unsigned short u;
    __builtin_memcpy(&u, &h, 2);
    return u;
}

__device__ __forceinline__ unsigned packbf2(float a, float b) {
    return (unsigned)f2bf(a) | ((unsigned)f2bf(b) << 16);
}

// ================= kernel A (k_pre): fused reduce3 + x3bf emission + x2bf + weights =========
// blocks [0,2304):   reduce3 (4 pos/block, shfl tree over k) + x3->bf16 emission (x3 read ONCE)
// blocks [2304,2340): x2->bf16. block 2340: W1_3/W2_3 -> bf16 MFMA B-fragments.
// r3[pos][2c]=max_{k not in {i,j}} (0-folded), [2c+1]=min (1-folded); i==j -> 0/1.
__global__ __launch_bounds__(256) void k_pre(const float* __restrict__ x2, const float* __restrict__ x3,
        const float* __restrict__ W1, const float* __restrict__ W2,
        float* __restrict__ r3, unsigned short* __restrict__ wf,
        unsigned short* __restrict__ x2bf, unsigned short* __restrict__ x3bf, int emit) {
    int tid = threadIdx.x, blk = blockIdx.x;
    if (blk < 2304) {
        int posl = tid >> 6, l = tid & 63;
        int pos = blk * 4 + posl;              // (b*48+i)*48+j < 9216
        int j = pos % NN, i = (pos / NN) % NN;
        int cq = l & 3, kkb = l >> 2;          // cq: channel quad, kkb: 0..15
        float4 ex = make_float4(0.f, 0.f, 0.f, 0.f);
        float4 fa = make_float4(1.f, 1.f, 1.f, 1.f);
        #pragma unroll
        for (int s = 0; s < 3; ++s) {
            int kk = kkb + s * 16;             // 0..47
            size_t idx = (((size_t)pos * NN + kk) << 4) + (cq << 2);
            float4 v = *(const float4*)(x3 + idx);
            if (emit) {
                uint2 pk;
                pk.x = packbf2(v.x, v.y);
                pk.y = packbf2(v.z, v.w);
                *(uint2*)(x3bf + idx) = pk;
            }
            bool ok = (i != j) && (kk != i) && (kk != j);
            ex.x = fmaxf(ex.x, ok ? v.x : 0.f);  fa.x = fminf(fa.x, ok ? v.x : 1.f);
            ex.y = fmaxf(ex.y, ok ? v.y : 0.f);  fa.y = fminf(fa.y, ok ? v.y : 1.f);
            ex.z = fmaxf(ex.z, ok ? v.z : 0.f);  fa.z = fminf(fa.z, ok ? v.z : 1.f);
            ex.w = fmaxf(ex.w, ok ? v.w : 0.f);  fa.w = fminf(fa.w, ok ? v.w : 1.f);
        }
        #pragma unroll
        for (int m = 4; m <= 32; m <<= 1) {
            ex.x = fmaxf(ex.x, __shfl_xor(ex.x, m));  fa.x = fminf(fa.x, __shfl_xor(fa.x, m));
            ex.y = fmaxf(ex.y, __shfl_xor(ex.y, m));  fa.y = fminf(fa.y, __shfl_xor(fa.y, m));
            ex.z = fmaxf(ex.z, __shfl_xor(ex.z, m));  fa.z = fminf(fa.z, __shfl_xor(fa.z, m));
            ex.w = fmaxf(ex.w, __shfl_xor(ex.w, m));  fa.w = fminf(fa.w, __shfl_xor(fa.w, m));
        }
        if (kkb == 0) {
            float* dst = r3 + ((size_t)pos << 5) + (cq << 3);
            *(float4*)dst       = make_float4(ex.x, fa.x, ex.y, fa.y);
            *(float4*)(dst + 4) = make_float4(ex.z, fa.z, ex.w, fa.w);
        }
    } else if (blk < 2340) {
        if (!emit) return;
        int bb = blk - 2304;                   // 0..35
        #pragma unroll
        for (int q = 0; q < 4; ++q) {
            int e = bb * 1024 + q * 256 + tid; // float4 chunk < 36864
            int off = e << 2;
            float4 v = *(const float4*)(x2 + off);
            uint2 pk;
            pk.x = packbf2(v.x, v.y);
            pk.y = packbf2(v.z, v.w);
            *(uint2*)(x2bf + off) = pk;
        }
    } else {
        for (int e = tid; e < 13312; e += 256) {
            unsigned short v;
            if (e < 12288) {
                int idx = e & 7, l = (e >> 3) & 63, r = e >> 9;   // r = nt*6+ks
                int ks = r % 6, nt = r / 6;
                v = f2bf(W1[(ks * 32 + ((l >> 4) << 3) + idx) * 64 + (nt << 4) + (l & 15)]);
            } else {
                int e2 = e - 12288;
                int idx = e2 & 7, l = (e2 >> 3) & 63, ks = e2 >> 9;
                v = f2bf(W2[(ks * 32 + ((l >> 4) << 3) + idx) * 16 + (l & 15)]);
            }
            wf[e] = v;
        }
    }
}

// ================= kernel B: g0 (block 0) + g1 w/ fused reduce2 (1..48) + g2 (49..624) ==========
__global__ __launch_bounds__(256) void k_small(const float* __restrict__ x0, const float* __restrict__ x1,
        const float* __restrict__ x2, const float* __restrict__ r3,
        const float* __restrict__ W1_0, const float* __restrict__ b1_0,
        const float* __restrict__ W2_0, const float* __restrict__ b2_0,
        const float* __restrict__ W1_1, const float* __restrict__ b1_1,
        const float* __restrict__ W2_1, const float* __restrict__ b2_1,
        const float* __restrict__ W1_2, const float* __restrict__ b1_2,
        const float* __restrict__ W2_2, const float* __restrict__ b2_2,
        float* __restrict__ out) {
    __shared__ __align__(16) float smem[8960];
    int tid = threadIdx.x;
    int blk = blockIdx.x;
    if (blk == 0) {
        float* st0 = smem;            // [4][48]
        float* sh0 = smem + 192;      // [4][64]
        int b = tid >> 6, sub = (tid >> 4) & 3, c = tid & 15;
        float ex = -INFINITY, fa = INFINITY;
        for (int ii = sub * 12; ii < sub * 12 + 12; ++ii) {
            float v = x1[(b * NN + ii) * 16 + c];
            ex = fmaxf(ex, v); fa = fminf(fa, v);
        }
        ex = fmaxf(ex, __shfl_xor(ex, 16)); fa = fminf(fa, __shfl_xor(fa, 16));
        ex = fmaxf(ex, __shfl_xor(ex, 32)); fa = fminf(fa, __shfl_xor(fa, 32));
        if (sub == 0) { st0[b * 48 + 16 + 2 * c] = ex; st0[b * 48 + 17 + 2 * c] = fa; }
        if (tid < 64) st0[(tid >> 4) * 48 + (tid & 15)] = x0[tid];
        __syncthreads();
        {
            int bb = tid >> 6, ln = tid & 63;
            float h = b1_0[ln];
            for (int cc = 0; cc < 48; ++cc) h += st0[bb * 48 + cc] * W1_0[cc * 64 + ln];
            sh0[bb * 64 + ln] = fmaxf(h, 0.f);
        }
        __syncthreads();
        if (tid < 64) {
            int bb = tid >> 4, o = tid & 15;
            float acc = b2_0[o];
            for (int tt = 0; tt < 64; ++tt) acc += sh0[bb * 64 + tt] * W2_0[tt * 16 + o];
            out[bb * 16 + o] = sigmoidf_(acc);
        }
    } else if (blk <= 48) {
        int grp = tid >> 6, ln = tid & 63;
        int row = (blk - 1) * 4 + grp;             // b*48+i, < 192
        int b = row / NN, i = row % NN;
        float* sin1 = smem + grp * 64;
        float* sh1  = smem + 256 + grp * 64;
        int c = ln & 15, q = ln >> 4;
        float ex = 0.f, fa = 1.f;
        const float* xb = x2 + (size_t)row * NN * 16 + c;
        for (int jj = q * 12; jj < q * 12 + 12; ++jj) {
            float v = xb[jj * 16];
            bool ok = (jj != i);
            ex = fmaxf(ex, ok ? v : 0.f); fa = fminf(fa, ok ? v : 1.f);
        }
        ex = fmaxf(ex, __shfl_xor(ex, 16)); fa = fminf(fa, __shfl_xor(fa, 16));
        ex = fmaxf(ex, __shfl_xor(ex, 32)); fa = fminf(fa, __shfl_xor(fa, 32));
        if (q == 0) { sin1[32 + 2 * c] = ex; sin1[33 + 2 * c] = fa; }
        if (ln < 16) sin1[ln] = x0[b * 16 + ln];
        else if (ln < 32) sin1[ln] = x1[row * 16 + (ln - 16)];
        __syncthreads();
        float h = b1_1[ln];
        #pragma unroll
        for (int c4 = 0; c4 < 64; c4 += 4) {
            float4 iv = *(const float4*)&sin1[c4];
            h += iv.x * W1_1[(c4 + 0) * 64 + ln] + iv.y * W1_1[(c4 + 1) * 64 + ln]
               + iv.z * W1_1[(c4 + 2) * 64 + ln] + iv.w * W1_1[(c4 + 3) * 64 + ln];
        }
        sh1[ln] = fmaxf(h, 0.f);
        __syncthreads();
        if (ln < 16) {
            float acc = b2_1[ln];
            #pragma unroll
            for (int tt = 0; tt < 64; ++tt) acc += sh1[tt] * W2_1[tt * 16 + ln];
            out[64 + row * 16 + ln] = sigmoidf_(acc);
        }
    } else {
        float* sW1  = smem;            // 8192
        float* sin_ = smem + 8192;     // [4][128]
        float* sh   = smem + 8704;     // [4][64]
        int wv = tid >> 6, ln = tid & 63;
        for (int p = tid; p < 8192; p += 256) sW1[p] = W1_2[p];
        float bias = b1_2[ln];
        __syncthreads();
        for (int rr = 0; rr < 4; ++rr) {
            int row = (blk - 49) * 16 + rr * 4 + wv;   // (b*48+i)*48+j
            int j = row % NN;
            int bi = row / NN;
            int i = bi % NN;
            int b = bi / NN;
            for (int cc = ln; cc < 128; cc += 64) {
                int half = cc >> 6, w = cc & 63;
                int a1 = half ? j : i;
                int a2 = half ? i : j;
                float v;
                if (w < 16)      v = x1[(b * NN + a1) * 16 + w];
                else if (w < 32) v = x2[((b * NN + a1) * NN + a2) * 16 + (w - 16)];
                else             v = r3[((size_t)(b * NN + a1) * NN + a2) * 32 + (w - 32)];
                sin_[wv * 128 + cc] = v;
            }
            __syncthreads();
            float h = bias;
            #pragma unroll
            for (int c4 = 0; c4 < 128; c4 += 4) {
                float4 iv = *(const float4*)&sin_[wv * 128 + c4];
                h += iv.x * sW1[(c4 + 0) * 64 + ln] + iv.y * sW1[(c4 + 1) * 64 + ln]
                   + iv.z * sW1[(c4 + 2) * 64 + ln] + iv.w * sW1[(c4 + 3) * 64 + ln];
            }
            sh[wv * 64 + ln] = fmaxf(h, 0.f);
            __syncthreads();
            if (ln < 16) {
                float acc = b2_2[ln];
                #pragma unroll
                for (int tt = 0; tt < 64; ++tt) acc += sh[wv * 64 + tt] * W2_2[tt * 16 + ln];
                out[3136 + row * 16 + ln] = sigmoidf_(acc);
            }
            __syncthreads();
        }
    }
}

// ================= kernel C (fast): group 3, mt-per-wave paired MFMA (r9-verified) =========
// Block = (pair i<=j, batch b), 192 threads = 3 waves, wave = M-tile mt. Each A-fragment
// load (16B/lane from bf16 x2bf/x3bf) feeds 8 MFMAs (4 N-tiles x 2 triples) via the chunk
// involution p1 = {2,4,0,5,1,3}. Epilogue bf16 conversion via v_cvt_pk (f2bf intrinsic).
__global__ __launch_bounds__(192) void k_g3d(const unsigned short* __restrict__ x2bf,
        const unsigned short* __restrict__ x3bf, const unsigned short* __restrict__ wf,
        const float* __restrict__ b1, const float* __restrict__ b2,
        float* __restrict__ out3) {
    __shared__ __align__(16) unsigned short sH[2][6 * 64 * 8];   // 12 KB

    int tid = threadIdx.x, mt = tid >> 6, l = tid & 63;   // wave = M-tile 0..2
    int pp = blockIdx.x, i = 0;
    while (pp >= NN - i) { pp -= NN - i; ++i; }
    int j = i + pp;                               // i <= j
    int b = blockIdx.y;

    // B fragments: all 4 N-tiles resident (96 VGPR), layer-2 frags (8 VGPR)
    bf16x8 w1f[4][6];
    #pragma unroll
    for (int nt = 0; nt < 4; ++nt)
        #pragma unroll
        for (int ks = 0; ks < 6; ++ks)
            w1f[nt][ks] = *(const bf16x8*)(wf + (((nt * 6 + ks) << 6) + l) * 8);
    bf16x8 w2f[2];
    #pragma unroll
    for (int ks = 0; ks < 2; ++ks)
        w2f[ks] = *(const bf16x8*)(wf + 12288 + ((ks << 6) + l) * 8);

    const int b2b = b * 36864;                    // b*48*48*16
    const int b3b = b * 1769472;                  // b*48*48*48*16
    // chunk order (triple (i,j)): c0=(i,j,k) c1=(i,k,j) c2=(j,i,k) c3=(k,i,j) c4=(j,k,i) c5=(k,j,i)
    const int cb2_[6] = { b2b + (i * NN + j) * 16, b2b + i * 768, b2b + (j * NN + i) * 16,
                          b2b + i * 16,            b2b + j * 768, b2b + j * 16 };
    const int cb3_[6] = { b3b + (i * NN + j) * 768, b3b + i * 36864 + j * 16, b3b + (j * NN + i) * 768,
                          b3b + i * 768 + j * 16,   b3b + j * 36864 + i * 16, b3b + j * 768 + i * 16 };
    const int s2_[6] = { 0, 16, 0, 768, 16, 768 };          // per-k element stride in x2bf
    const int s3_[6] = { 16, 768, 16, 36864, 768, 36864 };  // per-k element stride in x3bf

    int l15 = l & 15, g = l >> 4;
    bool isx2 = (g < 2);                          // lanes g=0,1: x2 chunk half; g=2,3: x3 half
    int goff = (g & 1) << 3;
    const unsigned short* bp = isx2 ? x2bf : x3bf;
    int off_[6];
    #pragma unroll
    for (int f = 0; f < 6; ++f) {
        int s = isx2 ? s2_[f] : s3_[f];
        int base = isx2 ? cb2_[f] : cb3_[f];
        off_[f] = base + ((mt << 4) + l15) * s + goff;   // row = mt*16 + l15
    }

    f32x4 acc[4][2];
    #pragma unroll
    for (int nt = 0; nt < 4; ++nt) {
        float bv = b1[(nt << 4) + l15];
        f32x4 t = {bv, bv, bv, bv};
        acc[nt][0] = t; acc[nt][1] = t;
    }
    const int p1[6] = { 2, 4, 0, 5, 1, 3 };

    #pragma unroll
    for (int f = 0; f < 6; ++f) {
        bf16x8 a = *(const bf16x8*)(bp + off_[f]);
        #pragma unroll
        for (int nt = 0; nt < 4; ++nt) {
            acc[nt][0] = __builtin_amdgcn_mfma_f32_16x16x32_bf16(a, w1f[nt][f], acc[nt][0], 0, 0, 0);
            acc[nt][1] = __builtin_amdgcn_mfma_f32_16x16x32_bf16(a, w1f[nt][p1[f]], acc[nt][1], 0, 0, 0);
        }
    }

    // ---- ReLU -> bf16 -> sH (layer-2 A-fragment order), both triples ----
    {
        int rbase = (l >> 4) << 2;
        #pragma unroll
        for (int tr = 0; tr < 2; ++tr) {
            #pragma unroll
            for (int nt = 0; nt < 4; ++nt) {
                int within = ((nt & 1) << 4) + l15;   // hc & 31
                int ks2 = nt >> 1;                    // hc >> 5
                int lhi = (within >> 3) << 4;
                int idx = within & 7;
                #pragma unroll
                for (int rg = 0; rg < 4; ++rg) {
                    float h = fmaxf(acc[nt][tr][rg], 0.0f);
                    int lp = rbase + rg + lhi;
                    sH[tr][((((mt << 1) + ks2) << 6) + lp) * 8 + idx] = f2bf(h);
                }
            }
        }
    }
    __syncthreads();

    // ---- layer 2: wave mt computes its M-tile, both triples ----
    {
        float bv2 = b2[l15];
        #pragma unroll
        for (int tr = 0; tr < 2; ++tr) {
            if (tr == 0 || i != j) {
                f32x4 acc2 = {bv2, bv2, bv2, bv2};
                #pragma unroll
                for (int ks = 0; ks < 2; ++ks) {
                    bf16x8 a = *(const bf16x8*)&sH[tr][((((mt << 1) + ks) << 6) + l) << 3];
                    acc2 = __builtin_amdgcn_mfma_f32_16x16x32_bf16(a, w2f[ks], acc2, 0, 0, 0);
                }
                int triple = tr ? ((b * NN + j) * NN + i) : ((b * NN + i) * NN + j);
                size_t obase = ((size_t)triple * NN + (mt << 4) + ((l >> 4) << 2)) * 16 + l15;
                #pragma unroll
                for (int rg = 0; rg < 4; ++rg)
                    out3[obase + (size_t)rg * 16] = sigmoidf_(acc2[rg]);
            }
        }
    }
}

// ================= kernel C (fallback): round-4-verified fp32 staged version =================
__global__ __launch_bounds__(256) void k_g3m(const float* __restrict__ x2, const float* __restrict__ x3,
                                             const unsigned short* __restrict__ wf,
                                             const float* __restrict__ b1, const float* __restrict__ b2,
                                             float* __restrict__ out3) {
    __shared__ __align__(16) unsigned short sA[18 * 64 * 8];
    __shared__ __align__(16) unsigned short sH[6 * 64 * 8];

    int tid = threadIdx.x;
    int wv = tid >> 6, l = tid & 63;
    int triple = blockIdx.x;
    int j = triple % NN;
    int bi = triple / NN;
    int i = bi % NN;
    int b = bi / NN;

    bf16x8 w1f[6];
    #pragma unroll
    for (int ks = 0; ks < 6; ++ks)
        w1f[ks] = *(const bf16x8*)(wf + (((wv * 6 + ks) << 6) + l) * 8);
    bf16x8 w2f[2];
    #pragma unroll
    for (int ks = 0; ks < 2; ++ks)
        w2f[ks] = *(const bf16x8*)(wf + 12288 + ((ks << 6) + l) * 8);

    const int x2b = b * NN * NN * 16;
    const int x3b = b * NN * NN * NN * 16;

    #pragma unroll
    for (int it = 0; it < 9; ++it) {
        int t = it * 256 + tid;
        int fs = __builtin_amdgcn_readfirstlane(t >> 7);
        int mt = fs / 6;
        int ks = fs - mt * 6;
        int lp = (t >> 1) & 63;
        int kk = (mt << 4) + (lp & 15);
        int w = ((lp >> 4) << 3) + ((t & 1) << 2);
        int a1, a2, a3;
        switch (ks) {
            case 0:  a1 = i;  a2 = j;  a3 = kk; break;
            case 1:  a1 = i;  a2 = kk; a3 = j;  break;
            case 2:  a1 = j;  a2 = i;  a3 = kk; break;
            case 3:  a1 = kk; a2 = i;  a3 = j;  break;
            case 4:  a1 = j;  a2 = kk; a3 = i;  break;
            default: a1 = kk; a2 = j;  a3 = i;  break;
        }
        const float* p2 = x2 + x2b + (a1 * NN + a2) * 16 + w;
        const float* p3 = x3 + x3b + ((a1 * NN + a2) * NN + a3) * 16 + (w - 16);
        const float* p = (w < 16) ? p2 : p3;
        float4 v = *(const float4*)p;
        uint2 pk;
        pk.x = packbf2(v.x, v.y);
        pk.y = packbf2(v.z, v.w);
        *(uint2*)&sA[t * 4] = pk;
    }
    __syncthreads();

    float bv = b1[(wv << 4) + (l & 15)];
    f32x4 acc0 = {bv, bv, bv, bv};
    f32x4 acc1 = acc0, acc2 = acc0;
    #pragma unroll
    for (int ks = 0; ks < 6; ++ks) {
        bf16x8 a0  = *(const bf16x8*)&sA[(((0 * 6 + ks) << 6) + l) << 3];
        bf16x8 a1_ = *(const bf16x8*)&sA[(((1 * 6 + ks) << 6) + l) << 3];
        bf16x8 a2_ = *(const bf16x8*)&sA[(((2 * 6 + ks) << 6) + l) << 3];
        acc0 = __builtin_amdgcn_mfma_f32_16x16x32_bf16(a0,  w1f[ks], acc0, 0, 0, 0);
        acc1 = __builtin_amdgcn_mfma_f32_16x16x32_bf16(a1_, w1f[ks], acc1, 0, 0, 0);
        acc2 = __builtin_amdgcn_mfma_f32_16x16x32_bf16(a2_, w1f[ks], acc2, 0, 0, 0);
    }

    {
        int within = ((wv & 1) << 4) + (l & 15);
        int ks2 = wv >> 1;
        int lhi = (within >> 3) << 4;
        int idx = within & 7;
        int rbase = (l >> 4) << 2;
        #pragma unroll
        for (int mt = 0; mt < 3; ++mt) {
            f32x4 a = (mt == 0) ? acc0 : (mt == 1) ? acc1 : acc2;
            #pragma unroll
            for (int rg = 0; rg < 4; ++rg) {
                float h = fmaxf(a[rg], 0.0f);
                int lp = rbase + rg + lhi;
                sH[((((mt << 1) + ks2) << 6) + lp) * 8 + idx] = f2bf(h);
            }
        }
    }
    __syncthreads();

    if (wv < 3) {
        int mt = wv;
        float bv2 = b2[l & 15];
        f32x4 acc = {bv2, bv2, bv2, bv2};
        #pragma unroll
        for (int ks = 0; ks < 2; ++ks) {
            bf16x8 a = *(const bf16x8*)&sH[((((mt << 1) + ks) << 6) + l) << 3];
            acc = __builtin_amdgcn_mfma_f32_16x16x32_bf16(a, w2f[ks], acc, 0, 0, 0);
        }
        size_t obase = ((size_t)triple * NN + (mt << 4) + ((l >> 4) << 2)) * 16 + (l & 15);
        #pragma unroll
        for (int rg = 0; rg < 4; ++rg)
            out3[obase + (size_t)rg * 16] = sigmoidf_(acc[rg]);
    }
}

extern "C" void kernel_launch(void* const* d_in, const int* in_sizes, int n_in,
                              void* d_out, int out_size, void* d_ws, size_t ws_size,
                              hipStream_t stream) {
    const float* x0 = (const float*)d_in[0];
    const float* x1 = (const float*)d_in[1];
    const float* x2 = (const float*)d_in[2];
    const float* x3 = (const float*)d_in[3];
    const float* W1_0 = (const float*)d_in[4];
    const float* b1_0 = (const float*)d_in[5];
    const float* W2_0 = (const float*)d_in[6];
    const float* b2_0 = (const float*)d_in[7];
    const float* W1_1 = (const float*)d_in[8];
    const float* b1_1 = (const float*)d_in[9];
    const float* W2_1 = (const float*)d_in[10];
    const float* b2_1 = (const float*)d_in[11];
    const float* W1_2 = (const float*)d_in[12];
    const float* b1_2 = (const float*)d_in[13];
    const float* W2_2 = (const float*)d_in[14];
    const float* b2_2 = (const float*)d_in[15];
    const float* W1_3 = (const float*)d_in[16];
    const float* b1_3 = (const float*)d_in[17];
    const float* W2_3 = (const float*)d_in[18];
    const float* b2_3 = (const float*)d_in[19];

    float* out = (float*)d_out;
    float* r3 = (float*)d_ws;                               // 294912 f32
    unsigned short* wf   = (unsigned short*)(r3 + 294912);  // 13312 bf16
    unsigned short* x2bf = wf + 13312;                      // 147456 bf16
    unsigned short* x3bf = x2bf + 147456;                   // 7077888 bf16
    size_t need = (size_t)294912 * 4 + (size_t)(13312 + 147456 + 7077888) * 2;  // ~15.66 MB
    int fast = (ws_size >= need) ? 1 : 0;

    hipLaunchKernelGGL(k_pre, dim3(2341), dim3(256), 0, stream,
                       x2, x3, W1_3, W2_3, r3, wf, x2bf, x3bf, fast);
    if (fast)
        hipLaunchKernelGGL(k_g3d, dim3(1176, 4), dim3(192), 0, stream,
                           x2bf, x3bf, wf, b1_3, b2_3, out + 150592);
    else
        hipLaunchKernelGGL(k_g3m, dim3(9216), dim3(256), 0, stream,
                           x2, x3, wf, b1_3, b2_3, out + 150592);
    hipLaunchKernelGGL(k_small, dim3(625), dim3(256), 0, stream,
                       x0, x1, x2, r3,
                       W1_0, b1_0, W2_0, b2_0,
                       W1_1, b1_1, W2_1, b2_1,
                       W1_2, b1_2, W2_2, b2_2,
                       out);
}